// Round 8
// baseline (683.642 us; speedup 1.0000x reference)
//
#include <hip/hip_runtime.h>
#include <hip/hip_bf16.h>

// Problem constants (reference: B=1024, F=128, E=256, HEAD_NUM=8, d=32)
// Reference dtypes: ALL fp32 (inputs and output). bf16 internally.
#define B_SZ 1024
#define F_SZ 128
#define E_SZ 256
#define H_NUM 8
#define D_SZ 32

typedef __bf16 bf16x8 __attribute__((ext_vector_type(8)));
typedef float f32x4 __attribute__((ext_vector_type(4)));
typedef unsigned short u16x4 __attribute__((ext_vector_type(4)));

__device__ __forceinline__ bf16x8 frag_at(const __hip_bfloat16* p) {
  return *reinterpret_cast<const bf16x8*>(p);
}

__device__ __forceinline__ bf16x8 pack_bf16x8(float4 a, float4 b) {
  bf16x8 r;
  r[0] = (__bf16)a.x; r[1] = (__bf16)a.y; r[2] = (__bf16)a.z; r[3] = (__bf16)a.w;
  r[4] = (__bf16)b.x; r[5] = (__bf16)b.y; r[6] = (__bf16)b.z; r[7] = (__bf16)b.w;
  return r;
}

__device__ __forceinline__ unsigned short f2bf_bits(float f) {
  __hip_bfloat16 b = __float2bfloat16(f);
  return *reinterpret_cast<unsigned short*>(&b);
}

__device__ __forceinline__ float bf_bits2f(unsigned short u) {
  unsigned int x = ((unsigned int)u) << 16;
  union { unsigned int i; float f; } c; c.i = x;
  return c.f;
}

// ---------------------------------------------------------------------------
// Prep: transpose the four fp32 E x E weights into bf16 WT[n][e] (n-major).
// ---------------------------------------------------------------------------
__global__ void transpose_weights(const float* __restrict__ W0,
                                  const float* __restrict__ W1,
                                  const float* __restrict__ W2,
                                  const float* __restrict__ W3,
                                  __hip_bfloat16* __restrict__ WT) {
  __shared__ float tile[64][65];
  const int wsel = blockIdx.x >> 4;
  const float* W = wsel == 0 ? W0 : wsel == 1 ? W1 : wsel == 2 ? W2 : W3;
  __hip_bfloat16* T = WT + wsel * (E_SZ * E_SZ);
  const int t = blockIdx.x & 15;
  const int tr = (t >> 2) * 64, tc = (t & 3) * 64;
  for (int k = 0; k < 16; ++k) {
    int fl = k * 256 + threadIdx.x;
    int lr = fl >> 6, lc = fl & 63;
    tile[lr][lc] = W[(tr + lr) * E_SZ + tc + lc];
  }
  __syncthreads();
  for (int k = 0; k < 16; ++k) {
    int fl = k * 256 + threadIdx.x;
    int lr = fl >> 6, lc = fl & 63;
    T[(tc + lr) * E_SZ + tr + lc] = __float2bfloat16(tile[lc][lr]);
  }
}

// ---------------------------------------------------------------------------
// v7: symmetric fused kernel, X-in-registers, 2 independent blocks/CU.
//  Measured facts driving this design:
//   v5: X-from-global = 663 MB fetch (HBM re-read per head)  -> X must stay on-chip
//   v6: producer/consumer = phase imbalance (proj is 4x attn) -> symmetric waves
//   v4/v6: 1 block/CU = all latency exposed                   -> need 2 blocks/CU
//  Structure: 512 thr = 8 waves; wave w owns f-rows [16w,16w+16).
//   prologue: X rows -> 8 bf16x8 register frags/lane (32 VGPR, read once).
//   per head: proj Q/K/V/R (reg-X x L2-resident W frags, 64 MFMA/wave)
//             -> barrier -> S^T=mfma(K,Q), lane-local softmax, P->own LDS
//             -> PV O^T=mfma(Vt,P) + residual/relu -> barrier.
//  LDS = 73,216 B (< 80 KB) -> 2 blocks/CU; launch_bounds(512,4) caps
//  VGPR<=128 -> 4 waves/SIMD from two INDEPENDENT blocks (barrier overlap).
//  2 barriers/head, 0 in prologue. No cvt_x dispatch (fp32->bf16 at load).
// ---------------------------------------------------------------------------
#define QST 40    // Qs/Ks stride (32+8) el: 80 B rows, 16-B aligned
#define RST 36    // Rs stride (32+4) el: 72 B rows, 8-B aligned
#define VST 136   // Vt stride (128+8) el: 272 B rows
#define PST 136   // Ps stride (128+8) el

#define QS_OFF 0
#define KS_OFF (128 * QST)                   // 5120
#define RS_OFF (KS_OFF + 128 * QST)          // 10240
#define VT_OFF (RS_OFF + 128 * RST)          // 14848
#define PS_OFF (VT_OFF + 32 * VST)           // 19200
#define SMEM_ELEMS (PS_OFF + 8 * 16 * PST)   // 36608 el = 73216 B

__global__ __launch_bounds__(512, 4)
void fused_attn(const float* __restrict__ X,
                const __hip_bfloat16* __restrict__ WT,
                float* __restrict__ out) {
  __shared__ __align__(16) __hip_bfloat16 smem[SMEM_ELEMS];
  __hip_bfloat16* const Qs = smem + QS_OFF;
  __hip_bfloat16* const Ks = smem + KS_OFF;
  __hip_bfloat16* const Rs = smem + RS_OFF;
  __hip_bfloat16* const Vt = smem + VT_OFF;

  const int tid  = threadIdx.x;
  const int wave = tid >> 6;          // 0..7
  const int lane = tid & 63;
  const int quad = lane >> 4;
  const int l16  = lane & 15;
  const int b    = blockIdx.x;
  const int fw   = wave * 16;         // this wave's 16 f-rows everywhere
  __hip_bfloat16* const Pw = smem + PS_OFF + fw * PST;

  // ---- prologue: X rows [fw, fw+16) -> register frags (fp32 -> bf16).
  // xf[ks] = X[fw+l16][ks*32 + quad*8 .. +8]; per (row,ks) the 4 quads cover
  // a contiguous 128-B span -> coalesced. Read ONCE per kernel.
  bf16x8 xf[8];
  {
    const float* Xr = X + ((size_t)b * F_SZ + fw + l16) * E_SZ + quad * 8;
    #pragma unroll
    for (int ks = 0; ks < 8; ++ks) {
      float4 a0 = *reinterpret_cast<const float4*>(Xr + ks * 32);
      float4 a1 = *reinterpret_cast<const float4*>(Xr + ks * 32 + 4);
      xf[ks] = pack_bf16x8(a0, a1);
    }
  }

  for (int h = 0; h < H_NUM; ++h) {
    // ========== Phase P: project Q/K/V/R rows [fw,fw+16) for head h =======
    #pragma unroll
    for (int mat = 0; mat < 4; ++mat) {
      const __hip_bfloat16* Wh =
          WT + mat * (E_SZ * E_SZ) + (h * D_SZ) * E_SZ;
      f32x4 acc0 = f32x4{0.f, 0.f, 0.f, 0.f};
      f32x4 acc1 = f32x4{0.f, 0.f, 0.f, 0.f};
      if (mat != 2) {
        // swapped: D[n][f] = mfma(W-rows, X-rows)
        #pragma unroll
        for (int ks = 0; ks < 8; ++ks) {
          const int ko = ks * 32 + quad * 8;
          bf16x8 aw0 = frag_at(Wh + l16 * E_SZ + ko);         // n 0..15
          bf16x8 aw1 = frag_at(Wh + (16 + l16) * E_SZ + ko);  // n 16..31
          acc0 = __builtin_amdgcn_mfma_f32_16x16x32_bf16(aw0, xf[ks], acc0, 0, 0, 0);
          acc1 = __builtin_amdgcn_mfma_f32_16x16x32_bf16(aw1, xf[ks], acc1, 0, 0, 0);
        }
        // D[n][f]: row(n)=quad*4+reg, col(f)=l16 -> store T[f][n], regs || n
        __hip_bfloat16* T = (mat == 0) ? Qs : (mat == 1) ? Ks : Rs;
        const int stride = (mat == 3) ? RST : QST;
        u16x4 pk0, pk1;
        #pragma unroll
        for (int reg = 0; reg < 4; ++reg) {
          pk0[reg] = f2bf_bits(acc0[reg]);
          pk1[reg] = f2bf_bits(acc1[reg]);
        }
        *reinterpret_cast<u16x4*>(&T[(fw + l16) * stride + quad * 4]) = pk0;
        *reinterpret_cast<u16x4*>(&T[(fw + l16) * stride + 16 + quad * 4]) = pk1;
      } else {
        // normal: D[f][d] = mfma(X-rows, W-rows) -> store Vt[d][f], regs || f
        #pragma unroll
        for (int ks = 0; ks < 8; ++ks) {
          const int ko = ks * 32 + quad * 8;
          bf16x8 aw0 = frag_at(Wh + l16 * E_SZ + ko);         // d 0..15
          bf16x8 aw1 = frag_at(Wh + (16 + l16) * E_SZ + ko);  // d 16..31
          acc0 = __builtin_amdgcn_mfma_f32_16x16x32_bf16(xf[ks], aw0, acc0, 0, 0, 0);
          acc1 = __builtin_amdgcn_mfma_f32_16x16x32_bf16(xf[ks], aw1, acc1, 0, 0, 0);
        }
        u16x4 pk0, pk1;
        #pragma unroll
        for (int reg = 0; reg < 4; ++reg) {
          pk0[reg] = f2bf_bits(acc0[reg]);
          pk1[reg] = f2bf_bits(acc1[reg]);
        }
        *reinterpret_cast<u16x4*>(&Vt[l16 * VST + fw + quad * 4]) = pk0;
        *reinterpret_cast<u16x4*>(&Vt[(16 + l16) * VST + fw + quad * 4]) = pk1;
      }
    }
    __syncthreads();

    // ========== Phase S: S^T = mfma(K,Q), lane-local softmax, P -> LDS ====
    {
      bf16x8 bq = frag_at(&Qs[(fw + l16) * QST + quad * 8]);
      f32x4 s[8];
      #pragma unroll
      for (int nt = 0; nt < 8; ++nt) {
        bf16x8 ak = frag_at(&Ks[(nt * 16 + l16) * QST + quad * 8]);
        s[nt] = __builtin_amdgcn_mfma_f32_16x16x32_bf16(
            ak, bq, f32x4{0.f, 0.f, 0.f, 0.f}, 0, 0, 0);
      }
      // lane holds S[f = fw+l16][k = nt*16 + quad*4 + reg] (32 values)
      float m = s[0][0];
      #pragma unroll
      for (int nt = 0; nt < 8; ++nt)
        #pragma unroll
        for (int reg = 0; reg < 4; ++reg) m = fmaxf(m, s[nt][reg]);
      m = fmaxf(m, __shfl_xor(m, 16));
      m = fmaxf(m, __shfl_xor(m, 32));
      float sum = 0.f;
      #pragma unroll
      for (int nt = 0; nt < 8; ++nt)
        #pragma unroll
        for (int reg = 0; reg < 4; ++reg) {
          float e = __expf(s[nt][reg] - m);
          s[nt][reg] = e;
          sum += e;
        }
      sum += __shfl_xor(sum, 16);
      sum += __shfl_xor(sum, 32);
      const float inv = 1.f / sum;
      #pragma unroll
      for (int nt = 0; nt < 8; ++nt) {
        u16x4 pk;
        #pragma unroll
        for (int reg = 0; reg < 4; ++reg) pk[reg] = f2bf_bits(s[nt][reg] * inv);
        *reinterpret_cast<u16x4*>(&Pw[l16 * PST + nt * 16 + quad * 4]) = pk;
      }
    }

    // ========== Phase PV: O^T = mfma(Vt, P) + fused residual/relu =========
    {
      f32x4 o[2];
      o[0] = f32x4{0.f, 0.f, 0.f, 0.f};
      o[1] = f32x4{0.f, 0.f, 0.f, 0.f};
      #pragma unroll
      for (int ks = 0; ks < 4; ++ks) {
        const int ko = ks * 32 + quad * 8;
        bf16x8 bp  = *reinterpret_cast<const bf16x8*>(Pw + l16 * PST + ko);
        bf16x8 av0 = frag_at(&Vt[l16 * VST + ko]);
        bf16x8 av1 = frag_at(&Vt[(16 + l16) * VST + ko]);
        o[0] = __builtin_amdgcn_mfma_f32_16x16x32_bf16(av0, bp, o[0], 0, 0, 0);
        o[1] = __builtin_amdgcn_mfma_f32_16x16x32_bf16(av1, bp, o[1], 0, 0, 0);
      }
      // lane holds O[f = fw+l16][d = nt*16 + quad*4 + reg]
      const size_t orow = ((size_t)b * F_SZ + fw + l16) * E_SZ + h * D_SZ;
      #pragma unroll
      for (int nt = 0; nt < 2; ++nt) {
        u16x4 rv = *reinterpret_cast<const u16x4*>(
            &Rs[(fw + l16) * RST + nt * 16 + quad * 4]);
        float4 st;
        float v0 = o[nt][0] + bf_bits2f(rv[0]);
        float v1 = o[nt][1] + bf_bits2f(rv[1]);
        float v2 = o[nt][2] + bf_bits2f(rv[2]);
        float v3 = o[nt][3] + bf_bits2f(rv[3]);
        st.x = (v0 < 0.f) ? 0.f : v0;
        st.y = (v1 < 0.f) ? 0.f : v1;
        st.z = (v2 < 0.f) ? 0.f : v2;
        st.w = (v3 < 0.f) ? 0.f : v3;
        *reinterpret_cast<float4*>(&out[orow + nt * 16 + quad * 4]) = st;
      }
    }
    __syncthreads();
  }
}

// ---------------------------------------------------------------------------
extern "C" void kernel_launch(void* const* d_in, const int* in_sizes, int n_in,
                              void* d_out, int out_size, void* d_ws, size_t ws_size,
                              hipStream_t stream) {
  const float* X  = (const float*)d_in[0];
  const float* Wq = (const float*)d_in[1];
  const float* Wk = (const float*)d_in[2];
  const float* Wv = (const float*)d_in[3];
  const float* Wr = (const float*)d_in[4];
  float* out = (float*)d_out;

  __hip_bfloat16* WT = (__hip_bfloat16*)d_ws;   // 4*256*256*2 = 512 KB

  (void)hipGetLastError();  // clear stale error state
  transpose_weights<<<64, 256, 0, stream>>>(Wq, Wk, Wv, Wr, WT);
  fused_attn<<<B_SZ, 512, 0, stream>>>(X, WT, out);

  // Launch-failure exfiltration (no-op when launches succeed).
  hipError_t err = hipGetLastError();
  if (err != hipSuccess) {
    hipMemsetAsync(d_out, 0x7F, 1024, stream);
  }
}

// Round 9
// 669.267 us; speedup vs baseline: 1.0215x; 1.0215x over previous
//
#include <hip/hip_runtime.h>
#include <hip/hip_bf16.h>

// Problem constants (reference: B=1024, F=128, E=256, HEAD_NUM=8, d=32)
// Reference dtypes: ALL fp32 (inputs and output). bf16 internally.
#define B_SZ 1024
#define F_SZ 128
#define E_SZ 256
#define H_NUM 8
#define D_SZ 32

typedef __bf16 bf16x8 __attribute__((ext_vector_type(8)));
typedef float f32x4 __attribute__((ext_vector_type(4)));
typedef unsigned short u16x4 __attribute__((ext_vector_type(4)));

__device__ __forceinline__ bf16x8 frag_at(const __hip_bfloat16* p) {
  return *reinterpret_cast<const bf16x8*>(p);
}

__device__ __forceinline__ bf16x8 pack_bf16x8(float4 a, float4 b) {
  bf16x8 r;
  r[0] = (__bf16)a.x; r[1] = (__bf16)a.y; r[2] = (__bf16)a.z; r[3] = (__bf16)a.w;
  r[4] = (__bf16)b.x; r[5] = (__bf16)b.y; r[6] = (__bf16)b.z; r[7] = (__bf16)b.w;
  return r;
}

__device__ __forceinline__ unsigned short f2bf_bits(float f) {
  __hip_bfloat16 b = __float2bfloat16(f);
  return *reinterpret_cast<unsigned short*>(&b);
}

__device__ __forceinline__ float bf_bits2f(unsigned short u) {
  unsigned int x = ((unsigned int)u) << 16;
  union { unsigned int i; float f; } c; c.i = x;
  return c.f;
}

// ---------------------------------------------------------------------------
// Prep: transpose the four fp32 E x E weights into bf16 WT[n][e] (n-major).
// ---------------------------------------------------------------------------
__global__ void transpose_weights(const float* __restrict__ W0,
                                  const float* __restrict__ W1,
                                  const float* __restrict__ W2,
                                  const float* __restrict__ W3,
                                  __hip_bfloat16* __restrict__ WT) {
  __shared__ float tile[64][65];
  const int wsel = blockIdx.x >> 4;
  const float* W = wsel == 0 ? W0 : wsel == 1 ? W1 : wsel == 2 ? W2 : W3;
  __hip_bfloat16* T = WT + wsel * (E_SZ * E_SZ);
  const int t = blockIdx.x & 15;
  const int tr = (t >> 2) * 64, tc = (t & 3) * 64;
  for (int k = 0; k < 16; ++k) {
    int fl = k * 256 + threadIdx.x;
    int lr = fl >> 6, lc = fl & 63;
    tile[lr][lc] = W[(tr + lr) * E_SZ + tc + lc];
  }
  __syncthreads();
  for (int k = 0; k < 16; ++k) {
    int fl = k * 256 + threadIdx.x;
    int lr = fl >> 6, lc = fl & 63;
    T[(tc + lr) * E_SZ + tr + lc] = __float2bfloat16(tile[lc][lr]);
  }
}

// ---------------------------------------------------------------------------
// v8: v7 with ONE change — phase P batches all 16 W-fragment loads of a mat
// into a statically-indexed register array BEFORE the MFMA chain.
//  v7's failure (measured): VGPR_Count=56 -> the compiler issued W loads in
//  pairs with vmcnt(0) waits inside the ks loop: two serialized ~250-cyc L2
//  round-trips per ks step, 64 per head per wave. MfmaUtil 6.5%, dur 530us.
//  v8: 16 back-to-back global_load_dwordx4 (vmcnt-counted drain), then 16
//  MFMAs. One pipelined ~300-cyc fill per mat instead of 8 serialized pairs.
//  Register budget: wf 64 + xf 32 + acc 8 + addr ~15 = ~119 <= 128, so
//  launch_bounds(512,4) still gives 4 waves/SIMD; mat loop NOT unrolled so
//  the scheduler cannot hoist 64 fragments and spill.
//  Everything else identical to v7 (X-in-regs read once, LDS 73 KB ->
//  2 blocks/CU, swapped-MFMA S/softmax/PV, vectorized stores).
// ---------------------------------------------------------------------------
#define QST 40    // Qs/Ks stride (32+8) el: 80 B rows, 16-B aligned
#define RST 36    // Rs stride (32+4) el: 72 B rows, 8-B aligned
#define VST 136   // Vt stride (128+8) el: 272 B rows
#define PST 136   // Ps stride (128+8) el

#define QS_OFF 0
#define KS_OFF (128 * QST)                   // 5120
#define RS_OFF (KS_OFF + 128 * QST)          // 10240
#define VT_OFF (RS_OFF + 128 * RST)          // 14848
#define PS_OFF (VT_OFF + 32 * VST)           // 19200
#define SMEM_ELEMS (PS_OFF + 8 * 16 * PST)   // 36608 el = 73216 B

__global__ __launch_bounds__(512, 4)
void fused_attn(const float* __restrict__ X,
                const __hip_bfloat16* __restrict__ WT,
                float* __restrict__ out) {
  __shared__ __align__(16) __hip_bfloat16 smem[SMEM_ELEMS];
  __hip_bfloat16* const Qs = smem + QS_OFF;
  __hip_bfloat16* const Ks = smem + KS_OFF;
  __hip_bfloat16* const Rs = smem + RS_OFF;
  __hip_bfloat16* const Vt = smem + VT_OFF;

  const int tid  = threadIdx.x;
  const int wave = tid >> 6;          // 0..7
  const int lane = tid & 63;
  const int quad = lane >> 4;
  const int l16  = lane & 15;
  const int b    = blockIdx.x;
  const int fw   = wave * 16;         // this wave's 16 f-rows everywhere
  __hip_bfloat16* const Pw = smem + PS_OFF + fw * PST;

  // ---- prologue: X rows [fw, fw+16) -> register frags (fp32 -> bf16).
  // xf[ks] = X[fw+l16][ks*32 + quad*8 .. +8]. Read ONCE per kernel.
  bf16x8 xf[8];
  {
    const float* Xr = X + ((size_t)b * F_SZ + fw + l16) * E_SZ + quad * 8;
    #pragma unroll
    for (int ks = 0; ks < 8; ++ks) {
      float4 a0 = *reinterpret_cast<const float4*>(Xr + ks * 32);
      float4 a1 = *reinterpret_cast<const float4*>(Xr + ks * 32 + 4);
      xf[ks] = pack_bf16x8(a0, a1);
    }
  }

  for (int h = 0; h < H_NUM; ++h) {
    // ========== Phase P: project Q/K/V/R rows [fw,fw+16) for head h =======
    #pragma unroll 1
    for (int mat = 0; mat < 4; ++mat) {
      const __hip_bfloat16* Wh =
          WT + mat * (E_SZ * E_SZ) + (h * D_SZ) * E_SZ;

      // Batch-load ALL 16 W fragments of this mat (static indices -> regs).
      // wf[2*ks+nt] = W[n = nt*16 + l16][k = ks*32 + quad*8 .. +8]
      bf16x8 wf[16];
      #pragma unroll
      for (int i = 0; i < 16; ++i) {
        const int nt = i & 1, ks = i >> 1;
        wf[i] = frag_at(Wh + (nt * 16 + l16) * E_SZ + ks * 32 + quad * 8);
      }

      f32x4 acc0 = f32x4{0.f, 0.f, 0.f, 0.f};
      f32x4 acc1 = f32x4{0.f, 0.f, 0.f, 0.f};
      if (mat != 2) {
        // swapped: D[n][f] = mfma(W-rows, X-rows)
        #pragma unroll
        for (int ks = 0; ks < 8; ++ks) {
          acc0 = __builtin_amdgcn_mfma_f32_16x16x32_bf16(wf[2 * ks],     xf[ks], acc0, 0, 0, 0);
          acc1 = __builtin_amdgcn_mfma_f32_16x16x32_bf16(wf[2 * ks + 1], xf[ks], acc1, 0, 0, 0);
        }
        // D[n][f]: row(n)=quad*4+reg, col(f)=l16 -> store T[f][n], regs || n
        __hip_bfloat16* T = (mat == 0) ? Qs : (mat == 1) ? Ks : Rs;
        const int stride = (mat == 3) ? RST : QST;
        u16x4 pk0, pk1;
        #pragma unroll
        for (int reg = 0; reg < 4; ++reg) {
          pk0[reg] = f2bf_bits(acc0[reg]);
          pk1[reg] = f2bf_bits(acc1[reg]);
        }
        *reinterpret_cast<u16x4*>(&T[(fw + l16) * stride + quad * 4]) = pk0;
        *reinterpret_cast<u16x4*>(&T[(fw + l16) * stride + 16 + quad * 4]) = pk1;
      } else {
        // normal: D[f][d] = mfma(X-rows, W-rows) -> store Vt[d][f], regs || f
        #pragma unroll
        for (int ks = 0; ks < 8; ++ks) {
          acc0 = __builtin_amdgcn_mfma_f32_16x16x32_bf16(xf[ks], wf[2 * ks],     acc0, 0, 0, 0);
          acc1 = __builtin_amdgcn_mfma_f32_16x16x32_bf16(xf[ks], wf[2 * ks + 1], acc1, 0, 0, 0);
        }
        u16x4 pk0, pk1;
        #pragma unroll
        for (int reg = 0; reg < 4; ++reg) {
          pk0[reg] = f2bf_bits(acc0[reg]);
          pk1[reg] = f2bf_bits(acc1[reg]);
        }
        *reinterpret_cast<u16x4*>(&Vt[l16 * VST + fw + quad * 4]) = pk0;
        *reinterpret_cast<u16x4*>(&Vt[(16 + l16) * VST + fw + quad * 4]) = pk1;
      }
    }
    __syncthreads();

    // ========== Phase S: S^T = mfma(K,Q), lane-local softmax, P -> LDS ====
    {
      bf16x8 bq = frag_at(&Qs[(fw + l16) * QST + quad * 8]);
      f32x4 s[8];
      #pragma unroll
      for (int nt = 0; nt < 8; ++nt) {
        bf16x8 ak = frag_at(&Ks[(nt * 16 + l16) * QST + quad * 8]);
        s[nt] = __builtin_amdgcn_mfma_f32_16x16x32_bf16(
            ak, bq, f32x4{0.f, 0.f, 0.f, 0.f}, 0, 0, 0);
      }
      // lane holds S[f = fw+l16][k = nt*16 + quad*4 + reg] (32 values)
      float m = s[0][0];
      #pragma unroll
      for (int nt = 0; nt < 8; ++nt)
        #pragma unroll
        for (int reg = 0; reg < 4; ++reg) m = fmaxf(m, s[nt][reg]);
      m = fmaxf(m, __shfl_xor(m, 16));
      m = fmaxf(m, __shfl_xor(m, 32));
      float sum = 0.f;
      #pragma unroll
      for (int nt = 0; nt < 8; ++nt)
        #pragma unroll
        for (int reg = 0; reg < 4; ++reg) {
          float e = __expf(s[nt][reg] - m);
          s[nt][reg] = e;
          sum += e;
        }
      sum += __shfl_xor(sum, 16);
      sum += __shfl_xor(sum, 32);
      const float inv = 1.f / sum;
      #pragma unroll
      for (int nt = 0; nt < 8; ++nt) {
        u16x4 pk;
        #pragma unroll
        for (int reg = 0; reg < 4; ++reg) pk[reg] = f2bf_bits(s[nt][reg] * inv);
        *reinterpret_cast<u16x4*>(&Pw[l16 * PST + nt * 16 + quad * 4]) = pk;
      }
    }

    // ========== Phase PV: O^T = mfma(Vt, P) + fused residual/relu =========
    {
      f32x4 o[2];
      o[0] = f32x4{0.f, 0.f, 0.f, 0.f};
      o[1] = f32x4{0.f, 0.f, 0.f, 0.f};
      #pragma unroll
      for (int ks = 0; ks < 4; ++ks) {
        const int ko = ks * 32 + quad * 8;
        bf16x8 bp  = *reinterpret_cast<const bf16x8*>(Pw + l16 * PST + ko);
        bf16x8 av0 = frag_at(&Vt[l16 * VST + ko]);
        bf16x8 av1 = frag_at(&Vt[(16 + l16) * VST + ko]);
        o[0] = __builtin_amdgcn_mfma_f32_16x16x32_bf16(av0, bp, o[0], 0, 0, 0);
        o[1] = __builtin_amdgcn_mfma_f32_16x16x32_bf16(av1, bp, o[1], 0, 0, 0);
      }
      // lane holds O[f = fw+l16][d = nt*16 + quad*4 + reg]
      const size_t orow = ((size_t)b * F_SZ + fw + l16) * E_SZ + h * D_SZ;
      #pragma unroll
      for (int nt = 0; nt < 2; ++nt) {
        u16x4 rv = *reinterpret_cast<const u16x4*>(
            &Rs[(fw + l16) * RST + nt * 16 + quad * 4]);
        float4 st;
        float v0 = o[nt][0] + bf_bits2f(rv[0]);
        float v1 = o[nt][1] + bf_bits2f(rv[1]);
        float v2 = o[nt][2] + bf_bits2f(rv[2]);
        float v3 = o[nt][3] + bf_bits2f(rv[3]);
        st.x = (v0 < 0.f) ? 0.f : v0;
        st.y = (v1 < 0.f) ? 0.f : v1;
        st.z = (v2 < 0.f) ? 0.f : v2;
        st.w = (v3 < 0.f) ? 0.f : v3;
        *reinterpret_cast<float4*>(&out[orow + nt * 16 + quad * 4]) = st;
      }
    }
    __syncthreads();
  }
}

// ---------------------------------------------------------------------------
extern "C" void kernel_launch(void* const* d_in, const int* in_sizes, int n_in,
                              void* d_out, int out_size, void* d_ws, size_t ws_size,
                              hipStream_t stream) {
  const float* X  = (const float*)d_in[0];
  const float* Wq = (const float*)d_in[1];
  const float* Wk = (const float*)d_in[2];
  const float* Wv = (const float*)d_in[3];
  const float* Wr = (const float*)d_in[4];
  float* out = (float*)d_out;

  __hip_bfloat16* WT = (__hip_bfloat16*)d_ws;   // 4*256*256*2 = 512 KB

  (void)hipGetLastError();  // clear stale error state
  transpose_weights<<<64, 256, 0, stream>>>(Wq, Wk, Wv, Wr, WT);
  fused_attn<<<B_SZ, 512, 0, stream>>>(X, WT, out);

  // Launch-failure exfiltration (no-op when launches succeed).
  hipError_t err = hipGetLastError();
  if (err != hipSuccess) {
    hipMemsetAsync(d_out, 0x7F, 1024, stream);
  }
}